// Round 2
// baseline (187.842 us; speedup 1.0000x reference)
//
#include <hip/hip_runtime.h>
#include <math.h>

#define DD    128
#define DI    170
#define DIP   176          // padded s_x / wf row: 44 float4 chunks
#define NC44  44
#define BB    4096
#define NNEG  5
#define ROWS  8
#define NBLK  (BB / ROWS)  // 512 blocks -> 2 blocks/CU
#define SQRT_D 11.3137084989847603904f   // sqrt(128)

__device__ __forceinline__ float wave_bcast_sum(float v) {
#pragma unroll
    for (int m = 1; m < 64; m <<= 1) v += __shfl_xor(v, m, 64);
    return v;
}

// Kernel 1: inverse L2 norms for W_hidden rows, W_gate rows, W_ff_out columns.
// Also zeroes the output accumulator (d_out is poisoned before every call).
__global__ __launch_bounds__(256) void norms_kernel(
    const float* __restrict__ W_hidden,
    const float* __restrict__ W_gate,
    const float* __restrict__ W_ff_out,
    float* __restrict__ inv_h,
    float* __restrict__ inv_g,
    float* __restrict__ inv_f,
    float* __restrict__ out)
{
    if (blockIdx.x == 0 && threadIdx.x == 0) out[0] = 0.0f;
    const int wave = threadIdx.x >> 6;
    const int lane = threadIdx.x & 63;
    const int v = blockIdx.x * 4 + wave;          // 0 .. 511 (510 used)
    if (v >= 3 * DI) return;
    float s;
    if (v < 2 * DI) {
        const float* W = (v < DI) ? W_hidden : W_gate;
        const int row = (v < DI) ? v : v - DI;
        float2 p = ((const float2*)(W + (long)row * DD))[lane];
        s = p.x * p.x + p.y * p.y;
    } else {
        const int c = v - 2 * DI;                 // column of W_ff_out (D x DI)
        float a = W_ff_out[(long)(2 * lane)     * DI + c];
        float b = W_ff_out[(long)(2 * lane + 1) * DI + c];
        s = a * a + b * b;
    }
    s = wave_bcast_sum(s);
    if (lane == 0) {
        float inv = rsqrtf(s);
        if (v < DI)            inv_h[v] = inv;
        else if (v < 2 * DI)   inv_g[v - DI] = inv;
        else                   inv_f[v - 2 * DI] = inv;
    }
}

__global__ __launch_bounds__(256) void main_kernel(
    const int*   __restrict__ input_ids,
    const int*   __restrict__ target_ids,
    const int*   __restrict__ neg_ids,
    const float* __restrict__ W_in,
    const float* __restrict__ W_out,
    const float* __restrict__ W_hidden,
    const float* __restrict__ W_gate,
    const float* __restrict__ W_ff_out,
    const float* __restrict__ hidden_scale,
    const float* __restrict__ gate_scale,
    const float* __restrict__ logit_scale,
    const float* __restrict__ inv_h,
    const float* __restrict__ inv_g,
    const float* __restrict__ inv_f,
    float* __restrict__ out)
{
    // Weight staging buffers: phase-2 slabs and phase-2b slab share storage.
    union SharedU {
        struct { float wh[DI][32]; float wg[DI][32]; } p2;   // 43520 B
        float wf[64][DIP];                                   // 45056 B
    };
    __shared__ __align__(16) SharedU u;
    __shared__ __align__(16) float s_emb[ROWS][DD];          // 4 KB
    __shared__ __align__(16) float s_x[ROWS][DIP];           // 5.5 KB (cols 170..175 zeroed)
    __shared__ __align__(16) float s_xout[ROWS][DD];         // 4 KB
    __shared__ float s_red[4];

    const int tid  = threadIdx.x;
    const int wave = tid >> 6;
    const int lane = tid & 63;
    const int b0   = blockIdx.x * ROWS;
    const int srow = lane >> 3;        // 0..7: sub-row within staging group
    const int schk = lane & 7;         // 0..7: 16B chunk within row

    // ---- Phase 1: gather + l2-normalize input embeddings into LDS ----
#pragma unroll
    for (int k = 0; k < ROWS / 4; ++k) {
        const int r  = wave + 4 * k;
        const int id = input_ids[b0 + r];
        float2 p = ((const float2*)(W_in + (long)id * DD))[lane];
        float s  = wave_bcast_sum(p.x * p.x + p.y * p.y);
        float inv = rsqrtf(s);
        s_emb[r][2 * lane]     = p.x * inv;
        s_emb[r][2 * lane + 1] = p.y * inv;
    }
    // (first __syncthreads below orders these writes before any read)

    // ---- Phase 2: h/g accumulators, staged through LDS in 4 d-slabs ----
    float ah[ROWS], ag[ROWS];
#pragma unroll
    for (int r = 0; r < ROWS; ++r) { ah[r] = 0.0f; ag[r] = 0.0f; }

    for (int slab = 0; slab < 4; ++slab) {
        // stage d-range [slab*32, slab*32+32) of all 170 rows, both matrices.
        // Wave instr: 8 rows x 128B contiguous each = 16 fully-used lines.
        // LDS store xor-swizzled by row so compute reads spread over 8 bank-groups.
        const long dofs = slab * 32 + schk * 4;
#pragma unroll
        for (int rnd = 0; rnd < 6; ++rnd) {
            const int i = rnd * 32 + wave * 8 + srow;
            if (i < DI) {
                const int pc = schk ^ (i & 7);
                float4 v = *(const float4*)(W_hidden + (long)i * DD + dofs);
                *(float4*)&u.p2.wh[i][pc * 4] = v;
                v = *(const float4*)(W_gate + (long)i * DD + dofs);
                *(float4*)&u.p2.wg[i][pc * 4] = v;
            }
        }
        __syncthreads();
        if (tid < DI) {
            const int sw = tid & 7;
            const float4* whr = (const float4*)&u.p2.wh[tid][0];
            const float4* wgr = (const float4*)&u.p2.wg[tid][0];
#pragma unroll
            for (int c = 0; c < 8; ++c) {
                const int pc = c ^ sw;           // undo storage swizzle; natural d order
                float4 h4 = whr[pc];
                float4 g4 = wgr[pc];
                const int dc = slab * 8 + c;
#pragma unroll
                for (int r = 0; r < ROWS; ++r) {
                    float4 e4 = ((const float4*)s_emb[r])[dc];   // broadcast across lanes
                    ah[r] += e4.x * h4.x + e4.y * h4.y + e4.z * h4.z + e4.w * h4.w;
                    ag[r] += e4.x * g4.x + e4.y * g4.y + e4.z * g4.z + e4.w * g4.w;
                }
            }
        }
        __syncthreads();
    }

    // ---- Phase 2 epilogue: scales + silu, write x (fold W_ff_out col norms) ----
    if (tid < DI) {
        const float hs = hidden_scale[tid] * inv_h[tid];
        const float gs = gate_scale[tid]   * inv_g[tid] * SQRT_D;
        const float fi = inv_f[tid];
#pragma unroll
        for (int r = 0; r < ROWS; ++r) {
            float h = ah[r] * hs;
            float g = ag[r] * gs;
            float x = (g / (1.0f + __expf(-g))) * h;   // silu(g) * h
            s_x[r][tid] = x * fi;
        }
    } else if (tid < DIP) {
#pragma unroll
        for (int r = 0; r < ROWS; ++r) s_x[r][tid] = 0.0f;   // zero pad (wf pad is 0 too)
    }

    // ---- Phase 2b: xout[r][dd] = sum_i x[r][i] * W_ff_out[dd][i], 2 dd-slabs ----
    const int r0 = wave;               // rows r0 and r0+4 per thread
    for (int slab = 0; slab < 2; ++slab) {
        // stage 64 rows of W_ff_out (680B each) into u.wf, rotation-stored,
        // zero-padded to 176 floats. float2 granularity (680B rows are 8B-aligned).
#pragma unroll
        for (int rr = 0; rr < 2; ++rr) {
            const int dlr = rr * 32 + wave * 8 + srow;      // local row 0..63
            const float* gsrc = W_ff_out + (long)(slab * 64 + dlr) * DI;
            for (int jr = 0; jr < 11; ++jr) {
                const int j = jr * 8 + schk;                // float2 idx 0..87
                float2 v = make_float2(0.0f, 0.0f);
                if (j < 85) v = *(const float2*)(gsrc + 2 * j);
                const int c  = j >> 1;                      // natural chunk 0..43
                int pc = c + dlr;
                pc %= NC44;                                 // rotation storage
                *(float2*)&u.wf[dlr][pc * 4 + (j & 1) * 2] = v;
            }
        }
        __syncthreads();
        {
            const int dl = lane;                            // row within slab
            float acc0 = 0.0f, acc1 = 0.0f;
            const float4* wfr = (const float4*)&u.wf[dl][0];
            const float4* x0r = (const float4*)&s_x[r0][0];      // broadcast rows
            const float4* x1r = (const float4*)&s_x[r0 + 4][0];
            int pc = (dl >= NC44) ? dl - NC44 : dl;
            for (int c = 0; c < NC44; ++c) {
                float4 w4 = wfr[pc];
                float4 xa = x0r[c];
                float4 xb = x1r[c];
                acc0 += w4.x * xa.x + w4.y * xa.y + w4.z * xa.z + w4.w * xa.w;
                acc1 += w4.x * xb.x + w4.y * xb.y + w4.z * xb.z + w4.w * xb.w;
                ++pc; if (pc == NC44) pc = 0;
            }
            const int dd = slab * 64 + dl;
            s_xout[r0][dd]     = acc0;
            s_xout[r0 + 4][dd] = acc1;
        }
        __syncthreads();
    }

    // ---- Phase 3: gathered logits + negative-sampling loss ----
    float wacc = 0.0f;
    for (int t = wave; t < ROWS * (1 + NNEG); t += 4) {
        const int r  = t / (1 + NNEG);
        const int jj = t % (1 + NNEG);
        const int bidx = b0 + r;
        const int id = (jj == 0) ? target_ids[bidx] : neg_ids[bidx * NNEG + jj - 1];
        const float* wrow = W_out + (long)id * DD;
        float w0 = wrow[lane], w1 = wrow[64 + lane];
        float x0 = s_xout[r][lane], x1 = s_xout[r][64 + lane];
        float dot = w0 * x0 + w1 * x1;
        float ss  = w0 * w0 + w1 * w1;
#pragma unroll
        for (int m = 1; m < 64; m <<= 1) {
            dot += __shfl_xor(dot, m, 64);
            ss  += __shfl_xor(ss,  m, 64);
        }
        const float logit = dot * rsqrtf(ss) * logit_scale[id] * SQRT_D;
        const float z  = (jj == 0) ? logit : -logit;
        const float ls = fminf(z, 0.0f) - log1pf(__expf(-fabsf(z)));   // stable log_sigmoid
        wacc += (jj == 0) ? ls * (1.0f / BB) : ls * (1.0f / (BB * NNEG));
    }
    if (lane == 0) s_red[wave] = wacc;
    __syncthreads();
    if (tid == 0) {
        float tot = s_red[0] + s_red[1] + s_red[2] + s_red[3];
        atomicAdd(out, -tot);
    }
}

extern "C" void kernel_launch(void* const* d_in, const int* in_sizes, int n_in,
                              void* d_out, int out_size, void* d_ws, size_t ws_size,
                              hipStream_t stream) {
    (void)in_sizes; (void)n_in; (void)out_size; (void)ws_size;
    const int*   input_ids    = (const int*)  d_in[0];
    const int*   target_ids   = (const int*)  d_in[1];
    const int*   neg_ids      = (const int*)  d_in[2];
    const float* W_in         = (const float*)d_in[3];
    const float* W_out        = (const float*)d_in[4];
    const float* W_hidden     = (const float*)d_in[5];
    const float* W_gate       = (const float*)d_in[6];
    const float* W_ff_out     = (const float*)d_in[7];
    const float* hidden_scale = (const float*)d_in[8];
    const float* gate_scale   = (const float*)d_in[9];
    const float* logit_scale  = (const float*)d_in[10];
    float* out   = (float*)d_out;
    float* inv_h = (float*)d_ws;
    float* inv_g = inv_h + DI;
    float* inv_f = inv_g + DI;

    norms_kernel<<<128, 256, 0, stream>>>(W_hidden, W_gate, W_ff_out,
                                          inv_h, inv_g, inv_f, out);
    main_kernel<<<NBLK, 256, 0, stream>>>(input_ids, target_ids, neg_ids,
                                          W_in, W_out, W_hidden, W_gate, W_ff_out,
                                          hidden_scale, gate_scale, logit_scale,
                                          inv_h, inv_g, inv_f, out);
}

// Round 3
// 166.475 us; speedup vs baseline: 1.1284x; 1.1284x over previous
//
#include <hip/hip_runtime.h>
#include <math.h>

#define DD    128
#define DI    170
#define DIP   176            // padded i-dimension (zero pad cols 170..175)
#define ND4   32             // DD/4 d-chunks
#define NI4   43             // ceil(DI/4) i-chunks (i=168..171 in chunk 42, 170/171 zero)
#define BB    4096
#define NNEG  5
#define ROWS  8
#define NBLK  (BB / ROWS)    // 512 blocks
#define SQRT_D 11.3137084989847603904f   // sqrt(128)

// workspace layout (floats)
#define WS_WHT 0                          // [32][176] float4
#define WS_WGT (ND4 * DIP * 4)            // 22528 floats
#define WS_WFT (2 * ND4 * DIP * 4)        // 45056 floats; [43][128] float4 = 22016 floats

__device__ __forceinline__ float wave_bcast_sum(float v) {
#pragma unroll
    for (int m = 1; m < 64; m <<= 1) v += __shfl_xor(v, m, 64);
    return v;
}

// Prep: per-call recompute of normalized+scale-folded TRANSPOSED weights into ws.
//  whT4[d4][i] = W_hidden[i][4d4+c] * inv_h[i]*hidden_scale[i]*inv_f[i]
//  wgT4[d4][i] = W_gate  [i][4d4+c] * inv_g[i]*gate_scale[i]*sqrt(D)
//  wfT4[i4][dd] = W_ff_out[dd][4i4+c]  (raw; col-norms folded via whT)
// Task per wave: t<170: column t (norms + whT/wgT writes); 170..212: wfT slab;
// 213/214: zero pads. Also zeroes out[0].
__global__ __launch_bounds__(256) void prep_kernel(
    const float* __restrict__ W_hidden,
    const float* __restrict__ W_gate,
    const float* __restrict__ W_ff_out,
    const float* __restrict__ hidden_scale,
    const float* __restrict__ gate_scale,
    float* __restrict__ ws,
    float* __restrict__ out)
{
    if (blockIdx.x == 0 && threadIdx.x == 0) out[0] = 0.0f;
    const int wave = threadIdx.x >> 6;
    const int lane = threadIdx.x & 63;
    const int t = blockIdx.x * 4 + wave;
    float* whT = ws + WS_WHT;
    float* wgT = ws + WS_WGT;
    float* wfT = ws + WS_WFT;

    if (t < DI) {
        const int v = t;
        // inverse norm of W_ff_out column v (128 entries, stride DI)
        float a = W_ff_out[(long)(2 * lane)     * DI + v];
        float b = W_ff_out[(long)(2 * lane + 1) * DI + v];
        float cf = wave_bcast_sum(a * a + b * b);
        // row norms of W_hidden / W_gate row v
        float2 ph = ((const float2*)(W_hidden + (long)v * DD))[lane];
        float2 pg = ((const float2*)(W_gate   + (long)v * DD))[lane];
        float sh = wave_bcast_sum(ph.x * ph.x + ph.y * ph.y);
        float sg = wave_bcast_sum(pg.x * pg.x + pg.y * pg.y);
        const float whs = rsqrtf(sh) * hidden_scale[v] * rsqrtf(cf);
        const float wgs = rsqrtf(sg) * gate_scale[v] * SQRT_D;
        // transposed write: lane holds d = 2*lane, 2*lane+1 -> d4 = lane>>1
        const int d4   = lane >> 1;
        const int half = lane & 1;                  // 0: comps {0,1}, 1: comps {2,3}
        float2* dh = (float2*)(whT + ((long)d4 * DIP + v) * 4 + half * 2);
        *dh = make_float2(ph.x * whs, ph.y * whs);
        float2* dg = (float2*)(wgT + ((long)d4 * DIP + v) * 4 + half * 2);
        *dg = make_float2(pg.x * wgs, pg.y * wgs);
    } else if (t < DI + NI4) {
        const int i4 = t - DI;                      // 0..42
#pragma unroll
        for (int rr = 0; rr < 2; ++rr) {
            const int dd = rr * 64 + lane;
            float4 v4;
            if (i4 < 42) {   // rows are 8B-aligned (680B): use two float2 loads
                float2 lo = *(const float2*)(W_ff_out + (long)dd * DI + 4 * i4);
                float2 hi = *(const float2*)(W_ff_out + (long)dd * DI + 4 * i4 + 2);
                v4 = make_float4(lo.x, lo.y, hi.x, hi.y);
            } else {         // i = 168,169 valid; 170,171 zero-pad
                float2 lo = *(const float2*)(W_ff_out + (long)dd * DI + 168);
                v4 = make_float4(lo.x, lo.y, 0.0f, 0.0f);
            }
            *(float4*)(wfT + ((long)i4 * DD + dd) * 4) = v4;
        }
    } else if (t == DI + NI4 || t == DI + NI4 + 1) {
        // zero pad columns 170..175 of whT / wgT
        float* base = (t == DI + NI4) ? whT : wgT;
        for (int idx = lane; idx < ND4 * 6; idx += 64) {
            const int d4 = idx / 6, c = idx % 6;
            *(float4*)(base + ((long)d4 * DIP + DI + c) * 4) =
                make_float4(0.0f, 0.0f, 0.0f, 0.0f);
        }
    }
}

__global__ __launch_bounds__(256) void main_kernel(
    const int*   __restrict__ input_ids,
    const int*   __restrict__ target_ids,
    const int*   __restrict__ neg_ids,
    const float* __restrict__ W_in,
    const float* __restrict__ W_out,
    const float* __restrict__ logit_scale,
    const float* __restrict__ ws,
    float* __restrict__ out)
{
    __shared__ __align__(16) float s_emb[ROWS][DD];    // 4 KB
    __shared__ __align__(16) float s_x[ROWS][DIP];     // 5.5 KB
    __shared__ __align__(16) float s_xout[ROWS][DD];   // 4 KB
    __shared__ float s_red[4];

    const int tid  = threadIdx.x;
    const int wave = tid >> 6;
    const int lane = tid & 63;
    const int b0   = blockIdx.x * ROWS;

    const float4* whT4 = (const float4*)(ws + WS_WHT);  // [32][176]
    const float4* wgT4 = (const float4*)(ws + WS_WGT);
    const float4* wfT4 = (const float4*)(ws + WS_WFT);  // [43][128]

    // ---- Phase 1: gather + l2-normalize input embeddings into LDS ----
#pragma unroll
    for (int k = 0; k < ROWS / 4; ++k) {
        const int r  = wave + 4 * k;
        const int id = input_ids[b0 + r];
        float2 p = ((const float2*)(W_in + (long)id * DD))[lane];
        float s  = wave_bcast_sum(p.x * p.x + p.y * p.y);
        float inv = rsqrtf(s);
        s_emb[r][2 * lane]     = p.x * inv;
        s_emb[r][2 * lane + 1] = p.y * inv;
    }
    __syncthreads();

    // ---- Phase 2: thread i computes h/g dots for all rows, fully coalesced
    //      weight reads (lane-consecutive float4 of whT4/wgT4 row d4) ----
    if (tid < DIP) {
        const int i = tid;
        float ah[ROWS], ag[ROWS];
#pragma unroll
        for (int r = 0; r < ROWS; ++r) { ah[r] = 0.0f; ag[r] = 0.0f; }
        for (int d4 = 0; d4 < ND4; ++d4) {
            float4 h4 = whT4[d4 * DIP + i];
            float4 g4 = wgT4[d4 * DIP + i];
#pragma unroll
            for (int r = 0; r < ROWS; ++r) {
                float4 e4 = ((const float4*)s_emb[r])[d4];   // uniform addr: broadcast
                ah[r] += e4.x * h4.x + e4.y * h4.y + e4.z * h4.z + e4.w * h4.w;
                ag[r] += e4.x * g4.x + e4.y * g4.y + e4.z * g4.z + e4.w * g4.w;
            }
        }
        // scales already folded into the transposed weights
#pragma unroll
        for (int r = 0; r < ROWS; ++r) {
            float h = ah[r];
            float g = ag[r];
            float x = (g / (1.0f + __expf(-g))) * h;   // silu(g) * h
            s_x[r][i] = x;                             // pad cols: h=g=0 -> 0
        }
    }
    __syncthreads();

    // ---- Phase 2b: xout[r][dd] = sum_i x[r][i] * wfT4[i][dd], coalesced ----
    {
        const int dd = tid & 127;
        const int r0 = tid >> 7;    // 0 or 1; rows r0, r0+2, r0+4, r0+6
        float acc[4];
#pragma unroll
        for (int k = 0; k < 4; ++k) acc[k] = 0.0f;
        for (int i4 = 0; i4 < NI4; ++i4) {
            float4 w4 = wfT4[i4 * DD + dd];
#pragma unroll
            for (int k = 0; k < 4; ++k) {
                const int r = r0 + 2 * k;
                float4 x4 = ((const float4*)s_x[r])[i4];     // broadcast
                acc[k] += w4.x * x4.x + w4.y * x4.y + w4.z * x4.z + w4.w * x4.w;
            }
        }
#pragma unroll
        for (int k = 0; k < 4; ++k) s_xout[r0 + 2 * k][dd] = acc[k];
    }
    __syncthreads();

    // ---- Phase 3: gathered logits + negative-sampling loss ----
    float wacc = 0.0f;
    for (int t = wave; t < ROWS * (1 + NNEG); t += 4) {
        const int r  = t / (1 + NNEG);
        const int jj = t % (1 + NNEG);
        const int bidx = b0 + r;
        const int id = (jj == 0) ? target_ids[bidx] : neg_ids[bidx * NNEG + jj - 1];
        const float* wrow = W_out + (long)id * DD;
        float w0 = wrow[lane], w1 = wrow[64 + lane];
        float x0 = s_xout[r][lane], x1 = s_xout[r][64 + lane];
        float dot = w0 * x0 + w1 * x1;
        float ss  = w0 * w0 + w1 * w1;
#pragma unroll
        for (int m = 1; m < 64; m <<= 1) {
            dot += __shfl_xor(dot, m, 64);
            ss  += __shfl_xor(ss,  m, 64);
        }
        const float logit = dot * rsqrtf(ss) * logit_scale[id] * SQRT_D;
        const float z  = (jj == 0) ? logit : -logit;
        const float ls = fminf(z, 0.0f) - log1pf(__expf(-fabsf(z)));   // stable log_sigmoid
        wacc += (jj == 0) ? ls * (1.0f / BB) : ls * (1.0f / (BB * NNEG));
    }
    if (lane == 0) s_red[wave] = wacc;
    __syncthreads();
    if (tid == 0) {
        float tot = s_red[0] + s_red[1] + s_red[2] + s_red[3];
        atomicAdd(out, -tot);
    }
}

extern "C" void kernel_launch(void* const* d_in, const int* in_sizes, int n_in,
                              void* d_out, int out_size, void* d_ws, size_t ws_size,
                              hipStream_t stream) {
    (void)in_sizes; (void)n_in; (void)out_size; (void)ws_size;
    const int*   input_ids    = (const int*)  d_in[0];
    const int*   target_ids   = (const int*)  d_in[1];
    const int*   neg_ids      = (const int*)  d_in[2];
    const float* W_in         = (const float*)d_in[3];
    const float* W_out        = (const float*)d_in[4];
    const float* W_hidden     = (const float*)d_in[5];
    const float* W_gate       = (const float*)d_in[6];
    const float* W_ff_out     = (const float*)d_in[7];
    const float* hidden_scale = (const float*)d_in[8];
    const float* gate_scale   = (const float*)d_in[9];
    const float* logit_scale  = (const float*)d_in[10];
    float* out = (float*)d_out;
    float* ws  = (float*)d_ws;     // needs 268 KB

    prep_kernel<<<54, 256, 0, stream>>>(W_hidden, W_gate, W_ff_out,
                                        hidden_scale, gate_scale, ws, out);
    main_kernel<<<NBLK, 256, 0, stream>>>(input_ids, target_ids, neg_ids,
                                          W_in, W_out, logit_scale, ws, out);
}

// Round 4
// 160.056 us; speedup vs baseline: 1.1736x; 1.0401x over previous
//
#include <hip/hip_runtime.h>
#include <math.h>

#define DD    128
#define DI    170
#define DIP   176            // padded i-dimension (zero pad cols 170..175)
#define ND4   32             // DD/4 d-chunks
#define NI4   43             // ceil(DI/4) i-chunks (i=168..171 in chunk 42, 170/171 zero)
#define BB    4096
#define NNEG  5
#define ROWS  8
#define NBLK  (BB / ROWS)    // 512 blocks
#define NTHR  512            // 8 waves/block -> 16 waves/CU at 2 blocks/CU
#define SQRT_D 11.3137084989847603904f   // sqrt(128)

// workspace layout (floats)
#define WS_WHT 0                          // [32][176] float4
#define WS_WGT (ND4 * DIP * 4)            // 22528 floats
#define WS_WFT (2 * ND4 * DIP * 4)        // 45056 floats; [43][128] float4 = 22016 floats

__device__ __forceinline__ float wave_bcast_sum(float v) {
#pragma unroll
    for (int m = 1; m < 64; m <<= 1) v += __shfl_xor(v, m, 64);
    return v;
}

// Prep: per-call recompute of normalized+scale-folded TRANSPOSED weights into ws.
//  whT4[d4][i] = W_hidden[i][4d4+c] * inv_h[i]*hidden_scale[i]*inv_f[i]
//  wgT4[d4][i] = W_gate  [i][4d4+c] * inv_g[i]*gate_scale[i]*sqrt(D)
//  wfT4[i4][dd] = W_ff_out[dd][4i4+c]  (raw; col-norms folded via whT)
__global__ __launch_bounds__(256) void prep_kernel(
    const float* __restrict__ W_hidden,
    const float* __restrict__ W_gate,
    const float* __restrict__ W_ff_out,
    const float* __restrict__ hidden_scale,
    const float* __restrict__ gate_scale,
    float* __restrict__ ws,
    float* __restrict__ out)
{
    if (blockIdx.x == 0 && threadIdx.x == 0) out[0] = 0.0f;
    const int wave = threadIdx.x >> 6;
    const int lane = threadIdx.x & 63;
    const int t = blockIdx.x * 4 + wave;
    float* whT = ws + WS_WHT;
    float* wgT = ws + WS_WGT;
    float* wfT = ws + WS_WFT;

    if (t < DI) {
        const int v = t;
        // inverse norm of W_ff_out column v (128 entries, stride DI)
        float a = W_ff_out[(long)(2 * lane)     * DI + v];
        float b = W_ff_out[(long)(2 * lane + 1) * DI + v];
        float cf = wave_bcast_sum(a * a + b * b);
        // row norms of W_hidden / W_gate row v
        float2 ph = ((const float2*)(W_hidden + (long)v * DD))[lane];
        float2 pg = ((const float2*)(W_gate   + (long)v * DD))[lane];
        float sh = wave_bcast_sum(ph.x * ph.x + ph.y * ph.y);
        float sg = wave_bcast_sum(pg.x * pg.x + pg.y * pg.y);
        const float whs = rsqrtf(sh) * hidden_scale[v] * rsqrtf(cf);
        const float wgs = rsqrtf(sg) * gate_scale[v] * SQRT_D;
        // transposed write: lane holds d = 2*lane, 2*lane+1 -> d4 = lane>>1
        const int d4   = lane >> 1;
        const int half = lane & 1;                  // 0: comps {0,1}, 1: comps {2,3}
        float2* dh = (float2*)(whT + ((long)d4 * DIP + v) * 4 + half * 2);
        *dh = make_float2(ph.x * whs, ph.y * whs);
        float2* dg = (float2*)(wgT + ((long)d4 * DIP + v) * 4 + half * 2);
        *dg = make_float2(pg.x * wgs, pg.y * wgs);
    } else if (t < DI + NI4) {
        const int i4 = t - DI;                      // 0..42
#pragma unroll
        for (int rr = 0; rr < 2; ++rr) {
            const int dd = rr * 64 + lane;
            float4 v4;
            if (i4 < 42) {   // rows are 8B-aligned (680B): use two float2 loads
                float2 lo = *(const float2*)(W_ff_out + (long)dd * DI + 4 * i4);
                float2 hi = *(const float2*)(W_ff_out + (long)dd * DI + 4 * i4 + 2);
                v4 = make_float4(lo.x, lo.y, hi.x, hi.y);
            } else {         // i = 168,169 valid; 170,171 zero-pad
                float2 lo = *(const float2*)(W_ff_out + (long)dd * DI + 168);
                v4 = make_float4(lo.x, lo.y, 0.0f, 0.0f);
            }
            *(float4*)(wfT + ((long)i4 * DD + dd) * 4) = v4;
        }
    } else if (t == DI + NI4 || t == DI + NI4 + 1) {
        // zero pad columns 170..175 of whT / wgT
        float* base = (t == DI + NI4) ? whT : wgT;
        for (int idx = lane; idx < ND4 * 6; idx += 64) {
            const int d4 = idx / 6, c = idx % 6;
            *(float4*)(base + ((long)d4 * DIP + DI + c) * 4) =
                make_float4(0.0f, 0.0f, 0.0f, 0.0f);
        }
    }
}

__global__ __launch_bounds__(NTHR, 4) void main_kernel(
    const int*   __restrict__ input_ids,
    const int*   __restrict__ target_ids,
    const int*   __restrict__ neg_ids,
    const float* __restrict__ W_in,
    const float* __restrict__ W_out,
    const float* __restrict__ logit_scale,
    const float* __restrict__ ws,
    float* __restrict__ out)
{
    __shared__ __align__(16) float s_emb[ROWS][DD];    // 4 KB
    __shared__ __align__(16) float s_x[ROWS][DIP];     // 5.5 KB
    __shared__ __align__(16) float s_xout[ROWS][DD];   // 4 KB
    __shared__ float s_partg[DIP][9];                  // g partials, stride 9 (bank-safe)
    __shared__ float s_red[8];

    const int tid  = threadIdx.x;
    const int wave = tid >> 6;
    const int lane = tid & 63;
    const int b0   = blockIdx.x * ROWS;

    const float4* whT4 = (const float4*)(ws + WS_WHT);  // [32][176]
    const float4* wgT4 = (const float4*)(ws + WS_WGT);
    const float4* wfT4 = (const float4*)(ws + WS_WFT);  // [43][128]

    // ---- Phase 1: gather + l2-normalize input embeddings; wave w -> row w ----
    {
        const int id = input_ids[b0 + wave];
        float2 p = ((const float2*)(W_in + (long)id * DD))[lane];
        float s  = wave_bcast_sum(p.x * p.x + p.y * p.y);
        float inv = rsqrtf(s);
        s_emb[wave][2 * lane]     = p.x * inv;
        s_emb[wave][2 * lane + 1] = p.y * inv;
    }
    __syncthreads();

    // ---- Phase 2: group 0 (tid<176) computes h-dots from whT, group 1
    //      (256<=tid<432) computes g-dots from wgT. Sequential d4 order
    //      per dot is identical to the single-group version. ----
    const bool g0 = (tid < DIP);
    const bool g1 = (tid >= 256 && tid < 256 + DIP);
    float a[ROWS];
#pragma unroll
    for (int r = 0; r < ROWS; ++r) a[r] = 0.0f;
    const int i = g0 ? tid : (g1 ? tid - 256 : -1);

    if (i >= 0) {
        const float4* wT = g0 ? whT4 : wgT4;
#pragma unroll 4
        for (int d4 = 0; d4 < ND4; ++d4) {
            float4 w4 = wT[d4 * DIP + i];        // lane-consecutive: coalesced
#pragma unroll
            for (int r = 0; r < ROWS; ++r) {
                float4 e4 = ((const float4*)s_emb[r])[d4];   // uniform addr: broadcast
                a[r] += e4.x * w4.x + e4.y * w4.y + e4.z * w4.z + e4.w * w4.w;
            }
        }
    }
    if (g1) {
#pragma unroll
        for (int r = 0; r < ROWS; ++r) s_partg[i][r] = a[r];
    }
    __syncthreads();

    if (g0) {
#pragma unroll
        for (int r = 0; r < ROWS; ++r) {
            float h = a[r];                       // scales (incl. inv_f) folded in prep
            float g = s_partg[i][r];
            float x = (g / (1.0f + __expf(-g))) * h;   // silu(g) * h
            s_x[r][i] = x;                        // pad cols i>=170: weights 0 -> x 0
        }
    }
    __syncthreads();

    // ---- Phase 2b: xout[r][dd] = sum_i x[r][i] * wfT4[i][dd]; 2 rows/thread ----
    {
        const int dd = tid & 127;
        const int r0 = tid >> 7;                  // 0..3; rows r0, r0+4
        float acc0 = 0.0f, acc1 = 0.0f;
#pragma unroll 4
        for (int i4 = 0; i4 < NI4; ++i4) {
            float4 w4 = wfT4[i4 * DD + dd];       // coalesced; L1-shared across r0 groups
            float4 xa = ((const float4*)s_x[r0])[i4];       // broadcast
            float4 xb = ((const float4*)s_x[r0 + 4])[i4];
            acc0 += w4.x * xa.x + w4.y * xa.y + w4.z * xa.z + w4.w * xa.w;
            acc1 += w4.x * xb.x + w4.y * xb.y + w4.z * xb.z + w4.w * xb.w;
        }
        s_xout[r0][dd]     = acc0;
        s_xout[r0 + 4][dd] = acc1;
    }
    __syncthreads();

    // ---- Phase 3: gathered logits + negative-sampling loss; 6 tasks/wave ----
    float wacc = 0.0f;
    for (int t = wave; t < ROWS * (1 + NNEG); t += 8) {
        const int r  = t / (1 + NNEG);
        const int jj = t % (1 + NNEG);
        const int bidx = b0 + r;
        const int id = (jj == 0) ? target_ids[bidx] : neg_ids[bidx * NNEG + jj - 1];
        const float* wrow = W_out + (long)id * DD;
        float w0 = wrow[lane], w1 = wrow[64 + lane];
        float x0 = s_xout[r][lane], x1 = s_xout[r][64 + lane];
        float dot = w0 * x0 + w1 * x1;
        float ss  = w0 * w0 + w1 * w1;
#pragma unroll
        for (int m = 1; m < 64; m <<= 1) {
            dot += __shfl_xor(dot, m, 64);
            ss  += __shfl_xor(ss,  m, 64);
        }
        const float logit = dot * rsqrtf(ss) * logit_scale[id] * SQRT_D;
        const float z  = (jj == 0) ? logit : -logit;
        const float ls = fminf(z, 0.0f) - log1pf(__expf(-fabsf(z)));   // stable log_sigmoid
        wacc += (jj == 0) ? ls * (1.0f / BB) : ls * (1.0f / (BB * NNEG));
    }
    if (lane == 0) s_red[wave] = wacc;
    __syncthreads();
    if (tid == 0) {
        float tot = s_red[0] + s_red[1] + s_red[2] + s_red[3]
                  + s_red[4] + s_red[5] + s_red[6] + s_red[7];
        atomicAdd(out, -tot);
    }
}

extern "C" void kernel_launch(void* const* d_in, const int* in_sizes, int n_in,
                              void* d_out, int out_size, void* d_ws, size_t ws_size,
                              hipStream_t stream) {
    (void)in_sizes; (void)n_in; (void)out_size; (void)ws_size;
    const int*   input_ids    = (const int*)  d_in[0];
    const int*   target_ids   = (const int*)  d_in[1];
    const int*   neg_ids      = (const int*)  d_in[2];
    const float* W_in         = (const float*)d_in[3];
    const float* W_out        = (const float*)d_in[4];
    const float* W_hidden     = (const float*)d_in[5];
    const float* W_gate       = (const float*)d_in[6];
    const float* W_ff_out     = (const float*)d_in[7];
    const float* hidden_scale = (const float*)d_in[8];
    const float* gate_scale   = (const float*)d_in[9];
    const float* logit_scale  = (const float*)d_in[10];
    float* out = (float*)d_out;
    float* ws  = (float*)d_ws;     // needs 268 KB

    prep_kernel<<<54, 256, 0, stream>>>(W_hidden, W_gate, W_ff_out,
                                        hidden_scale, gate_scale, ws, out);
    main_kernel<<<NBLK, NTHR, 0, stream>>>(input_ids, target_ids, neg_ids,
                                           W_in, W_out, logit_scale, ws, out);
}

// Round 5
// 155.935 us; speedup vs baseline: 1.2046x; 1.0264x over previous
//
#include <hip/hip_runtime.h>
#include <math.h>

#define DD    128
#define DI    170
#define DIP   176            // padded i-dimension (zero pad cols 170..175)
#define ND4   32             // DD/4 d-chunks
#define NI4P  44             // padded i4 chunk count (chunk 42 half, 43 zero)
#define BB    4096
#define NNEG  5
#define ROWS  4
#define NBLK  (BB / ROWS)    // 1024 blocks -> 4 blocks/CU at 8 waves/SIMD
#define NTHR  512
#define SQRT_D 11.3137084989847603904f   // sqrt(128)

// workspace layout (floats)
#define WS_WHT 0                          // [32][176] float4
#define WS_WGT (ND4 * DIP * 4)            // 22528 floats
#define WS_WFT (2 * ND4 * DIP * 4)        // 45056 floats; [44][128] float4

__device__ __forceinline__ float wave_bcast_sum(float v) {
#pragma unroll
    for (int m = 1; m < 64; m <<= 1) v += __shfl_xor(v, m, 64);
    return v;
}

// Prep: per-call recompute of normalized+scale-folded TRANSPOSED weights into ws.
//  whT4[d4][i]  = W_hidden[i][4d4+c] * inv_h[i]*hidden_scale[i]*inv_f[i]
//  wgT4[d4][i]  = W_gate  [i][4d4+c] * inv_g[i]*gate_scale[i]*sqrt(D)
//  wfT4[i4][dd] = W_ff_out[dd][4i4+c]  (raw; col-norms folded via whT)
// 216 wave-tasks over 54 blocks.
__global__ __launch_bounds__(256) void prep_kernel(
    const float* __restrict__ W_hidden,
    const float* __restrict__ W_gate,
    const float* __restrict__ W_ff_out,
    const float* __restrict__ hidden_scale,
    const float* __restrict__ gate_scale,
    float* __restrict__ ws,
    float* __restrict__ out)
{
    if (blockIdx.x == 0 && threadIdx.x == 0) out[0] = 0.0f;
    const int wave = threadIdx.x >> 6;
    const int lane = threadIdx.x & 63;
    const int t = blockIdx.x * 4 + wave;
    float* whT = ws + WS_WHT;
    float* wgT = ws + WS_WGT;
    float* wfT = ws + WS_WFT;

    if (t < DI) {
        const int v = t;
        // inverse norm of W_ff_out column v (128 entries, stride DI)
        float a = W_ff_out[(long)(2 * lane)     * DI + v];
        float b = W_ff_out[(long)(2 * lane + 1) * DI + v];
        float cf = wave_bcast_sum(a * a + b * b);
        // row norms of W_hidden / W_gate row v
        float2 ph = ((const float2*)(W_hidden + (long)v * DD))[lane];
        float2 pg = ((const float2*)(W_gate   + (long)v * DD))[lane];
        float sh = wave_bcast_sum(ph.x * ph.x + ph.y * ph.y);
        float sg = wave_bcast_sum(pg.x * pg.x + pg.y * pg.y);
        const float whs = rsqrtf(sh) * hidden_scale[v] * rsqrtf(cf);
        const float wgs = rsqrtf(sg) * gate_scale[v] * SQRT_D;
        // transposed write: lane holds d = 2*lane, 2*lane+1 -> d4 = lane>>1
        const int d4   = lane >> 1;
        const int half = lane & 1;                  // 0: comps {0,1}, 1: comps {2,3}
        float2* dh = (float2*)(whT + ((long)d4 * DIP + v) * 4 + half * 2);
        *dh = make_float2(ph.x * whs, ph.y * whs);
        float2* dg = (float2*)(wgT + ((long)d4 * DIP + v) * 4 + half * 2);
        *dg = make_float2(pg.x * wgs, pg.y * wgs);
    } else if (t < DI + NI4P) {
        const int i4 = t - DI;                      // 0..43
#pragma unroll
        for (int rr = 0; rr < 2; ++rr) {
            const int dd = rr * 64 + lane;
            float4 v4;
            if (i4 < 42) {   // rows are 8B-aligned (680B): use two float2 loads
                float2 lo = *(const float2*)(W_ff_out + (long)dd * DI + 4 * i4);
                float2 hi = *(const float2*)(W_ff_out + (long)dd * DI + 4 * i4 + 2);
                v4 = make_float4(lo.x, lo.y, hi.x, hi.y);
            } else if (i4 == 42) {  // i = 168,169 valid; 170,171 zero-pad
                float2 lo = *(const float2*)(W_ff_out + (long)dd * DI + 168);
                v4 = make_float4(lo.x, lo.y, 0.0f, 0.0f);
            } else {                // i4 == 43: all pad
                v4 = make_float4(0.0f, 0.0f, 0.0f, 0.0f);
            }
            *(float4*)(wfT + ((long)i4 * DD + dd) * 4) = v4;
        }
    } else if (t == DI + NI4P || t == DI + NI4P + 1) {
        // zero pad columns 170..175 of whT / wgT
        float* base = (t == DI + NI4P) ? whT : wgT;
        for (int idx = lane; idx < ND4 * 6; idx += 64) {
            const int d4 = idx / 6, c = idx % 6;
            *(float4*)(base + ((long)d4 * DIP + DI + c) * 4) =
                make_float4(0.0f, 0.0f, 0.0f, 0.0f);
        }
    }
}

__global__ __launch_bounds__(NTHR, 8) void main_kernel(
    const int*   __restrict__ input_ids,
    const int*   __restrict__ target_ids,
    const int*   __restrict__ neg_ids,
    const float* __restrict__ W_in,
    const float* __restrict__ W_out,
    const float* __restrict__ logit_scale,
    const float* __restrict__ ws,
    float* __restrict__ out)
{
    __shared__ __align__(16) float s_emb[ROWS][DD];    // 2 KB
    __shared__ __align__(16) float s_x[ROWS][DIP];     // 2.75 KB
    __shared__ __align__(16) float s_xout[ROWS][DD];   // 2 KB
    __shared__ __align__(16) float s_pp[4][ROWS][DD];  // 8 KB: 2b split-i partials
    __shared__ float s_partg[DIP][ROWS + 1];           // stride 5: bank-safe
    __shared__ float s_red[8];

    const int tid  = threadIdx.x;
    const int wave = tid >> 6;
    const int lane = tid & 63;
    const int b0   = blockIdx.x * ROWS;

    const float4* whT4 = (const float4*)(ws + WS_WHT);  // [32][176]
    const float4* wgT4 = (const float4*)(ws + WS_WGT);
    const float4* wfT4 = (const float4*)(ws + WS_WFT);  // [44][128]

    // ---- Phase 1: gather + l2-normalize input embeddings; wave w -> row w ----
    if (wave < ROWS) {
        const int id = input_ids[b0 + wave];
        float2 p = ((const float2*)(W_in + (long)id * DD))[lane];
        float s  = wave_bcast_sum(p.x * p.x + p.y * p.y);
        float inv = rsqrtf(s);
        s_emb[wave][2 * lane]     = p.x * inv;
        s_emb[wave][2 * lane + 1] = p.y * inv;
    }
    __syncthreads();

    // ---- Phase 2: group 0 (tid<176) h-dots from whT; group 1 (256..431)
    //      g-dots from wgT. Sequential d4=0..31 order per dot (exact). ----
    const bool g0 = (tid < DIP);
    const bool g1 = (tid >= 256 && tid < 256 + DIP);
    float a[ROWS];
#pragma unroll
    for (int r = 0; r < ROWS; ++r) a[r] = 0.0f;
    const int i = g0 ? tid : (g1 ? tid - 256 : -1);

    if (i >= 0) {
        const float4* wT = g0 ? whT4 : wgT4;
#pragma unroll 4
        for (int d4 = 0; d4 < ND4; ++d4) {
            float4 w4 = wT[d4 * DIP + i];        // lane-consecutive: coalesced
#pragma unroll
            for (int r = 0; r < ROWS; ++r) {
                float4 e4 = ((const float4*)s_emb[r])[d4];   // uniform addr: broadcast
                a[r] += e4.x * w4.x + e4.y * w4.y + e4.z * w4.z + e4.w * w4.w;
            }
        }
    }
    if (g1) {
#pragma unroll
        for (int r = 0; r < ROWS; ++r) s_partg[i][r] = a[r];
    }
    __syncthreads();

    if (g0) {
#pragma unroll
        for (int r = 0; r < ROWS; ++r) {
            float h = a[r];                       // scales (incl. inv_f) folded in prep
            float g = s_partg[i][r];
            float x = (g / (1.0f + __expf(-g))) * h;   // silu(g) * h
            s_x[r][i] = x;                        // pad cols i>=170: weights 0 -> x 0
        }
    }
    __syncthreads();

    // ---- Phase 2b: split-i. Quarter q reads i4 in [11q, 11q+11), computes
    //      partials for ALL rows; wfT streamed exactly once per block. ----
    {
        const int dd = tid & 127;
        const int q  = tid >> 7;                  // 0..3
        float acc[ROWS];
#pragma unroll
        for (int r = 0; r < ROWS; ++r) acc[r] = 0.0f;
        const int i4lo = q * 11;
#pragma unroll 4
        for (int k = 0; k < 11; ++k) {
            const int i4 = i4lo + k;
            float4 w4 = wfT4[i4 * DD + dd];       // coalesced
#pragma unroll
            for (int r = 0; r < ROWS; ++r) {
                float4 x4 = ((const float4*)s_x[r])[i4];     // broadcast
                acc[r] += w4.x * x4.x + w4.y * x4.y + w4.z * x4.z + w4.w * x4.w;
            }
        }
#pragma unroll
        for (int r = 0; r < ROWS; ++r) s_pp[q][r][dd] = acc[r];
    }
    __syncthreads();
    {
        const int dd = tid & 127;
        const int r  = tid >> 7;                  // 0..3
        // fixed q order: deterministic accumulation
        float v = ((s_pp[0][r][dd] + s_pp[1][r][dd]) + s_pp[2][r][dd]) + s_pp[3][r][dd];
        s_xout[r][dd] = v;
    }
    __syncthreads();

    // ---- Phase 3: gathered logits + negative-sampling loss; 3 tasks/wave ----
    float wacc = 0.0f;
    for (int t = wave; t < ROWS * (1 + NNEG); t += 8) {
        const int r  = t / (1 + NNEG);
        const int jj = t % (1 + NNEG);
        const int bidx = b0 + r;
        const int id = (jj == 0) ? target_ids[bidx] : neg_ids[bidx * NNEG + jj - 1];
        const float* wrow = W_out + (long)id * DD;
        float w0 = wrow[lane], w1 = wrow[64 + lane];
        float x0 = s_xout[r][lane], x1 = s_xout[r][64 + lane];
        float dot = w0 * x0 + w1 * x1;
        float ss  = w0 * w0 + w1 * w1;
#pragma unroll
        for (int m = 1; m < 64; m <<= 1) {
            dot += __shfl_xor(dot, m, 64);
            ss  += __shfl_xor(ss,  m, 64);
        }
        const float logit = dot * rsqrtf(ss) * logit_scale[id] * SQRT_D;
        const float z  = (jj == 0) ? logit : -logit;
        const float ls = fminf(z, 0.0f) - log1pf(__expf(-fabsf(z)));   // stable log_sigmoid
        wacc += (jj == 0) ? ls * (1.0f / BB) : ls * (1.0f / (BB * NNEG));
    }
    if (lane == 0) s_red[wave] = wacc;
    __syncthreads();
    if (tid == 0) {
        float tot = s_red[0] + s_red[1] + s_red[2] + s_red[3]
                  + s_red[4] + s_red[5] + s_red[6] + s_red[7];
        atomicAdd(out, -tot);
    }
}

extern "C" void kernel_launch(void* const* d_in, const int* in_sizes, int n_in,
                              void* d_out, int out_size, void* d_ws, size_t ws_size,
                              hipStream_t stream) {
    (void)in_sizes; (void)n_in; (void)out_size; (void)ws_size;
    const int*   input_ids    = (const int*)  d_in[0];
    const int*   target_ids   = (const int*)  d_in[1];
    const int*   neg_ids      = (const int*)  d_in[2];
    const float* W_in         = (const float*)d_in[3];
    const float* W_out        = (const float*)d_in[4];
    const float* W_hidden     = (const float*)d_in[5];
    const float* W_gate       = (const float*)d_in[6];
    const float* W_ff_out     = (const float*)d_in[7];
    const float* hidden_scale = (const float*)d_in[8];
    const float* gate_scale   = (const float*)d_in[9];
    const float* logit_scale  = (const float*)d_in[10];
    float* out = (float*)d_out;
    float* ws  = (float*)d_ws;     // needs 270 KB

    prep_kernel<<<54, 256, 0, stream>>>(W_hidden, W_gate, W_ff_out,
                                        hidden_scale, gate_scale, ws, out);
    main_kernel<<<NBLK, NTHR, 0, stream>>>(input_ids, target_ids, neg_ids,
                                           W_in, W_out, logit_scale, ws, out);
}